// Round 1
// 700.889 us; speedup vs baseline: 1.3488x; 1.3488x over previous
//
#include <hip/hip_runtime.h>
#include <math.h>

#define NCLS 64
#define KS 5
#define DD 256
#define NQ 8192   // NCLS*128
#define KNB 10
#define QK 12     // per-chunk candidate list depth (need >=10 for exact containment)
#define NCH 8     // column chunks per row (1024 cols each)
#define CAND 96   // NCH * QK

typedef __attribute__((ext_vector_type(8))) short short8;   // 8 bf16 bit-patterns (4 VGPRs)
typedef __attribute__((ext_vector_type(4))) float f32x4;    // MFMA C/D frag

// row index in x (fp32 row units) of query g
__device__ __forceinline__ int qrow(int g) { return (g >> 7) * 133 + KS + (g & 127); }

__device__ __forceinline__ unsigned short bf16_rne(float f) {
    unsigned int u = __float_as_uint(f);
    u += 0x7fffu + ((u >> 16) & 1u);
    return (unsigned short)(u >> 16);
}

__device__ __forceinline__ float blk_reduce_sum(float v, float* red) {
    int t = threadIdx.x;
    red[t] = v; __syncthreads();
    for (int off = 128; off > 0; off >>= 1) {
        if (t < off) red[t] += red[t + off];
        __syncthreads();
    }
    float r = red[0];
    __syncthreads();
    return r;
}

__device__ __forceinline__ float blk_reduce_max(float v, float* red) {
    int t = threadIdx.x;
    red[t] = v; __syncthreads();
    for (int off = 128; off > 0; off >>= 1) {
        if (t < off) red[t] = fmaxf(red[t], red[t + off]);
        __syncthreads();
    }
    float r = red[0];
    __syncthreads();
    return r;
}

// ---------- K0: NORMALIZED bf16 cast of query rows + qInv ----------
// xh rows are pre-divided by their norm so K4's MFMA output is the cosine
// directly: no per-row (ainv) or per-col (qc) scaling needed in the scan.
__global__ __launch_bounds__(256) void split_kernel(const float* __restrict__ x,
                                                    unsigned short* __restrict__ xh,
                                                    float* __restrict__ qInv) {
    __shared__ float red[256];
    int g = blockIdx.x, t = threadIdx.x;
    float v = x[(long)qrow(g) * DD + t];
    float n2 = blk_reduce_sum(v * v, red);
    float inv = 1.f / sqrtf(n2);
    xh[g * DD + t] = bf16_rne(v * inv);
    if (t == 0) qInv[g] = inv;
}

// ---------- K1: proto, pn, self_sim ----------
__global__ __launch_bounds__(256) void proto_kernel(const float* __restrict__ x,
                                                    float* proto, float* pn, float* selfs) {
    __shared__ float red[256];
    int c = blockIdx.x, t = threadIdx.x;
    float s = 0.f;
    for (int j = 0; j < KS; j++) s += x[(long)(c * 133 + j) * DD + t];
    float p = s / 5.0f;
    proto[c * DD + t] = p;
    float n2 = blk_reduce_sum(p * p, red);
    float pv = p / sqrtf(n2);
    pn[c * DD + t] = pv;
    float ss = blk_reduce_sum(pv * pv, red);
    if (t == 0) selfs[c] = ss;
}

// ---------- K2: pre_sim argmax per query ----------
__global__ __launch_bounds__(256) void presim_kernel(const float* __restrict__ x,
                                                     const float* __restrict__ qInv,
                                                     const float* __restrict__ pn,
                                                     float* pre_max, int* pre_label) {
    __shared__ float qs[256];
    __shared__ float part[256];
    __shared__ float sims[64];
    int g = blockIdx.x, t = threadIdx.x;
    qs[t] = x[(long)qrow(g) * DD + t];
    __syncthreads();
    int c = t >> 2, tl = t & 3;
    float s = 0.f;
    for (int u = 0; u < 64; u++) s += qs[tl * 64 + u] * pn[c * DD + tl * 64 + u];
    part[t] = s; __syncthreads();
    if (tl == 0) sims[c] = part[t] + part[t + 1] + part[t + 2] + part[t + 3];
    __syncthreads();
    if (t == 0) {
        float best = sims[0]; int bi = 0;
        for (int c2 = 1; c2 < 64; c2++)
            if (sims[c2] > best) { best = sims[c2]; bi = c2; }
        pre_max[g] = best * qInv[g];
        pre_label[g] = bi;
    }
}

// ---------- K3: adapted prototypes — LDS-compacted member list ----------
__global__ __launch_bounds__(256) void adapt_proto_kernel(const float* __restrict__ x,
                                                          const float* __restrict__ proto,
                                                          const float* __restrict__ selfs,
                                                          const float* __restrict__ pre_max,
                                                          const int* __restrict__ pre_label,
                                                          float* apn) {
    __shared__ int lst[NQ];     // 32 KB (worst case: all queries in one class)
    __shared__ float red[256];
    __shared__ int cnt_s;
    int c = blockIdx.x, t = threadIdx.x;
    if (t == 0) cnt_s = 0;
    __syncthreads();
    float lm = -INFINITY;
    for (int g = t; g < NQ; g += 256) {
        if (pre_label[g] == c) {
            int p = atomicAdd(&cnt_s, 1);
            lst[p] = g;
            lm = fmaxf(lm, pre_max[g]);
        }
    }
    float m = fmaxf(blk_reduce_max(lm, red), selfs[c]);   // barrier publishes lst/cnt_s
    int cnt = cnt_s;
    float ls = 0.f;
    for (int e = t; e < cnt; e += 256) ls += expf(pre_max[lst[e]] - m);
    float es = expf(selfs[c] - m);
    float Z = blk_reduce_sum(ls, red) + es;
    float acc = es * proto[c * DD + t];
    #pragma unroll 2
    for (int e = 0; e < cnt; e++) {
        int g = lst[e];
        acc += expf(pre_max[g] - m) * x[(long)qrow(g) * DD + t];
    }
    float ap = acc / Z;
    float n2 = blk_reduce_sum(ap * ap, red);
    apn[c * DD + t] = ap / sqrtf(n2);
}

// ---------- K4: bf16 MFMA coarse cosines -> per-chunk top-12 candidates ----------
// 8 column chunks of 1024 (was 4 quarters of 2048): grid 1024 blocks, 33.8 KB LDS
// -> 4 blocks/CU = 16 waves/CU (2x prior occupancy; latency-bound kernel).
// xh is pre-normalized, so MFMA acc IS the cosine: scan = ds_read + cmp + insert.
// NO barriers at all: LDS is wave-private (in-order per-wave DS ops).
__global__ __launch_bounds__(256, 4) void simtopk_kernel(const unsigned short* __restrict__ xh,
                                                         int* __restrict__ topi4) {
    __shared__ float Sw[4][2112];   // per-wave scores 16x132 (reused as merge dump) 33.8 KB

    const int t = threadIdx.x;
    const int b = blockIdx.x;
    const int rb = b >> 3;          // 128 row-blocks of 64 rows
    const int ch = b & 7;           // column chunk
    const int row0 = rb * 64;
    const int col0 = ch * 1024;

    const int wv = t >> 6;
    const int lane = t & 63;
    const int qd = lane >> 4;
    const int nn = lane & 15;

    // A fragments: lane holds A[m=nn][k=kc*32+qd*8 ..+7], rows row0+16wv..+15
    const int arow = (row0 + wv * 16 + nn) * DD;
    short8 ah[8];
    #pragma unroll
    for (int kc = 0; kc < 8; kc++)
        ah[kc] = *(const short8*)(xh + arow + kc * 32 + qd * 8);

    const int srow = lane >> 2;    // scan row 0..15
    const int slot = lane & 3;     // scan column slot

    float Lv[QK]; int Li[QK];
    #pragma unroll
    for (int s = 0; s < QK; s++) { Lv[s] = -INFINITY; Li[s] = 0; }
    float thr = -INFINITY;

    float* S = &Sw[wv][0];

    for (int mt = 0; mt < 8; mt++) {
        const int jb = col0 + mt * 128;
        #pragma unroll 2
        for (int st = 0; st < 8; st++) {
            f32x4 acc = {0.f, 0.f, 0.f, 0.f};
            const int cb = (jb + st * 16 + nn) * DD;
            #pragma unroll
            for (int kc = 0; kc < 8; kc++) {
                short8 bfrag = *(const short8*)(xh + cb + kc * 32 + qd * 8);
                acc = __builtin_amdgcn_mfma_f32_16x16x32_bf16(ah[kc], bfrag, acc, 0, 0, 0);
            }
            // C/D: col=nn, row=4qd+r. Already cosine (pre-normalized xh). 2-way LDS = free.
            #pragma unroll
            for (int r = 0; r < 4; r++)
                S[(4 * qd + r) * 132 + st * 16 + nn] = acc[r];
        }
        // wave-private scan: lane (srow,slot) handles cols jj*4+slot (bank = 2-way)
        #pragma unroll 8
        for (int jj = 0; jj < 32; jj++) {
            const int j = jj * 4 + slot;
            float v = S[srow * 132 + j];
            if (v > thr) {
                float cv = v; int ci = jb + j;
                #pragma unroll
                for (int p = 0; p < QK; p++) {   // bubble insert, register-resident
                    bool sw = (cv > Lv[p]);
                    float tv = Lv[p]; int tix = Li[p];
                    Lv[p] = sw ? cv : Lv[p];
                    Li[p] = sw ? ci : Li[p];
                    cv = sw ? tv : cv;
                    ci = sw ? tix : ci;
                }
                thr = Lv[QK - 1];
            }
        }
    }

    // dump lists to wave-private LDS (stride 13: kills 8-way write conflict of
    // stride 12), then lanes 0..15 merge their row's 4 slot-lists
    float* dv = &Sw[wv][0];
    int*   di = (int*)&Sw[wv][1024];
    #pragma unroll
    for (int s = 0; s < QK; s++) { dv[lane * 13 + s] = Lv[s]; di[lane * 13 + s] = Li[s]; }
    if (lane < 16) {
        const int g = row0 + wv * 16 + lane;
        const int b0 = (lane * 4 + 0) * 13;
        const int b1 = (lane * 4 + 1) * 13;
        const int b2 = (lane * 4 + 2) * 13;
        const int b3 = (lane * 4 + 3) * 13;
        int p0 = 0, p1 = 0, p2 = 0, p3 = 0;
        for (int s = 0; s < QK; s++) {
            float v0 = (p0 < QK) ? dv[b0 + p0] : -INFINITY;
            float v1 = (p1 < QK) ? dv[b1 + p1] : -INFINITY;
            float v2 = (p2 < QK) ? dv[b2 + p2] : -INFINITY;
            float v3 = (p3 < QK) ? dv[b3 + p3] : -INFINITY;
            int i0 = (p0 < QK) ? di[b0 + p0] : 0x7fffffff;
            int i1 = (p1 < QK) ? di[b1 + p1] : 0x7fffffff;
            int i2 = (p2 < QK) ? di[b2 + p2] : 0x7fffffff;
            int i3 = (p3 < QK) ? di[b3 + p3] : 0x7fffffff;
            float bv = v0; int bi = i0; int bw = 0;
            if (v1 > bv || (v1 == bv && i1 < bi)) { bv = v1; bi = i1; bw = 1; }
            if (v2 > bv || (v2 == bv && i2 < bi)) { bv = v2; bi = i2; bw = 2; }
            if (v3 > bv || (v3 == bv && i3 < bi)) { bv = v3; bi = i3; bw = 3; }
            topi4[g * CAND + ch * QK + s] = bi;
            if (bw == 0) p0++; else if (bw == 1) p1++; else if (bw == 2) p2++; else p3++;
        }
    }
}

// ---------- K5: exact fp32 rescoring (float4 loads) + top-10 ----------
// block = 192 threads = 2 rows x 96 candidates
__global__ __launch_bounds__(192) void rescore_kernel(const float* __restrict__ x,
                                                      const float* __restrict__ qInv,
                                                      const int* __restrict__ topi4,
                                                      float* __restrict__ topv,
                                                      int* __restrict__ topi) {
    __shared__ float sc[2][CAND];
    __shared__ int   si[2][CAND];
    const int t  = threadIdx.x;
    const int lr = (t >= CAND) ? 1 : 0;  // local row 0..1
    const int c  = t - lr * CAND;        // candidate slot 0..95
    const int g  = blockIdx.x * 2 + lr;
    int j = topi4[g * CAND + c];
    if ((unsigned)j >= NQ) j = 0;        // defensive clamp
    const float4* a4 = (const float4*)(x + (long)qrow(g) * DD);
    const float4* b4 = (const float4*)(x + (long)qrow(j) * DD);
    float dot = 0.f;
    #pragma unroll 8
    for (int k = 0; k < DD / 4; k++) {
        float4 a = a4[k], bq = b4[k];
        dot = fmaf(a.x, bq.x, dot);
        dot = fmaf(a.y, bq.y, dot);
        dot = fmaf(a.z, bq.z, dot);
        dot = fmaf(a.w, bq.w, dot);
    }
    sc[lr][c] = (dot * qInv[j]) * qInv[g];
    si[lr][c] = j;
    __syncthreads();
    if (t < 2) {
        const int r = t;
        float Lv[KNB]; int Li[KNB];
        for (int s = 0; s < KNB; s++) { Lv[s] = -INFINITY; Li[s] = 0x7fffffff; }
        for (int q = 0; q < CAND; q++) {
            float v = sc[r][q]; int idx = si[r][q];
            if (v > Lv[KNB - 1] || (v == Lv[KNB - 1] && idx < Li[KNB - 1])) {
                int p = KNB - 1;
                while (p > 0 && (Lv[p - 1] < v || (Lv[p - 1] == v && Li[p - 1] > idx))) {
                    Lv[p] = Lv[p - 1]; Li[p] = Li[p - 1]; p--;
                }
                Lv[p] = v; Li[p] = idx;
            }
        }
        const int gg = blockIdx.x * 2 + r;
        for (int s = 0; s < KNB; s++) {
            topv[gg * KNB + s] = Lv[s];
            topi[gg * KNB + s] = Li[s];
        }
    }
}

// ---------- K6: mutual-kNN softmax, adapted query, final cos sims ----------
__global__ __launch_bounds__(256) void final_kernel(const float* __restrict__ x,
                                                    const float* __restrict__ apn,
                                                    const float* __restrict__ topv,
                                                    const int* __restrict__ topi,
                                                    const float* __restrict__ tao_raw,
                                                    float* out) {
    __shared__ float tv[KNB]; __shared__ int ti[KNB]; __shared__ float w[KNB];
    __shared__ float aq[256]; __shared__ float red[256];
    int i = blockIdx.x, t = threadIdx.x;
    if (t < KNB) {
        tv[t] = topv[i * KNB + t];
        int j = topi[i * KNB + t];
        ti[t] = ((unsigned)j < NQ) ? j : 0;
    }
    __syncthreads();
    if (t < KNB) {
        int j = ti[t];
        bool mut = false;
        for (int s = 0; s < KNB; s++) mut = mut || (topi[j * KNB + s] == i);
        w[t] = mut ? tv[t] : -INFINITY;
    }
    __syncthreads();
    if (t == 0) {
        float m = -INFINITY;
        for (int s = 0; s < KNB; s++) m = fmaxf(m, w[s]);
        float e[KNB]; float Z = 0.f;
        for (int s = 0; s < KNB; s++) { e[s] = expf(w[s] - m); Z += e[s]; }
        for (int s = 0; s < KNB; s++) w[s] = e[s] / Z;
    }
    __syncthreads();
    float a = 0.f;
    for (int s = 0; s < KNB; s++) {
        float ws = w[s];
        if (ws != 0.f) a += ws * x[(long)qrow(ti[s]) * DD + t];
    }
    aq[t] = a;
    float n2 = blk_reduce_sum(a * a, red);
    float inv = 1.f / sqrtf(n2);
    int c = t >> 2, tl = t & 3;
    float sdot = 0.f;
    for (int u = 0; u < 64; u++) sdot += aq[tl * 64 + u] * apn[c * DD + tl * 64 + u];
    red[t] = sdot; __syncthreads();
    if (tl == 0) {
        float sv = red[t] + red[t + 1] + red[t + 2] + red[t + 3];
        out[i * NCLS + c] = tao_raw[0] * sv * inv;
    }
}

extern "C" void kernel_launch(void* const* d_in, const int* in_sizes, int n_in,
                              void* d_out, int out_size, void* d_ws, size_t ws_size,
                              hipStream_t stream) {
    (void)in_sizes; (void)n_in; (void)out_size;
    const float* x   = (const float*)d_in[0];
    const float* tao = (const float*)d_in[1];
    float* out = (float*)d_out;

    char* ws = (char*)d_ws;
    size_t off = 0;
    auto carve = [&](size_t bytes) {
        void* p = ws + off;
        off = (off + bytes + 255) & ~(size_t)255;
        return p;
    };
    float*          proto   = (float*)carve(NCLS * DD * 4);
    float*          pn      = (float*)carve(NCLS * DD * 4);
    float*          selfs   = (float*)carve(NCLS * 4);
    float*          qInv    = (float*)carve(NQ * 4);
    float*          pre_max = (float*)carve(NQ * 4);
    int*            pre_lab = (int*)carve(NQ * 4);
    float*          apn     = (float*)carve(NCLS * DD * 4);
    unsigned short* xh      = (unsigned short*)carve((size_t)NQ * DD * 2);
    int*            topi4   = (int*)carve((size_t)NQ * CAND * 4);
    float*          topv    = (float*)carve((size_t)NQ * KNB * 4);
    int*            topi    = (int*)carve((size_t)NQ * KNB * 4);
    if (off > ws_size) return;

    split_kernel<<<NQ, 256, 0, stream>>>(x, xh, qInv);
    proto_kernel<<<NCLS, 256, 0, stream>>>(x, proto, pn, selfs);
    presim_kernel<<<NQ, 256, 0, stream>>>(x, qInv, pn, pre_max, pre_lab);
    adapt_proto_kernel<<<NCLS, 256, 0, stream>>>(x, proto, selfs, pre_max, pre_lab, apn);
    simtopk_kernel<<<NQ / 64 * NCH, 256, 0, stream>>>(xh, topi4);
    rescore_kernel<<<NQ / 2, 192, 0, stream>>>(x, qInv, topi4, topv, topi);
    final_kernel<<<NQ, 256, 0, stream>>>(x, apn, topv, topi, tao, out);
}

// Round 2
// 644.822 us; speedup vs baseline: 1.4661x; 1.0869x over previous
//
#include <hip/hip_runtime.h>
#include <math.h>

#define NCLS 64
#define KS 5
#define DD 256
#define NQ 8192   // NCLS*128
#define KNB 10
#define QK 12     // per-chunk candidate list depth (need >=10 for exact containment)
#define NCH 8     // column chunks per row (1024 cols each)
#define CAND 96   // NCH * QK

typedef __attribute__((ext_vector_type(8))) short short8;   // 8 bf16 bit-patterns (4 VGPRs)
typedef __attribute__((ext_vector_type(4))) float f32x4;    // MFMA C/D frag

// row index in x (fp32 row units) of query g
__device__ __forceinline__ int qrow(int g) { return (g >> 7) * 133 + KS + (g & 127); }

__device__ __forceinline__ unsigned short bf16_rne(float f) {
    unsigned int u = __float_as_uint(f);
    u += 0x7fffu + ((u >> 16) & 1u);
    return (unsigned short)(u >> 16);
}

__device__ __forceinline__ float blk_reduce_sum(float v, float* red) {
    int t = threadIdx.x;
    red[t] = v; __syncthreads();
    for (int off = 128; off > 0; off >>= 1) {
        if (t < off) red[t] += red[t + off];
        __syncthreads();
    }
    float r = red[0];
    __syncthreads();
    return r;
}

__device__ __forceinline__ float blk_reduce_max(float v, float* red) {
    int t = threadIdx.x;
    red[t] = v; __syncthreads();
    for (int off = 128; off > 0; off >>= 1) {
        if (t < off) red[t] = fmaxf(red[t], red[t + off]);
        __syncthreads();
    }
    float r = red[0];
    __syncthreads();
    return r;
}

// ---------- K0: NORMALIZED bf16 cast of query rows + qInv ----------
__global__ __launch_bounds__(256) void split_kernel(const float* __restrict__ x,
                                                    unsigned short* __restrict__ xh,
                                                    float* __restrict__ qInv) {
    __shared__ float red[256];
    int g = blockIdx.x, t = threadIdx.x;
    float v = x[(long)qrow(g) * DD + t];
    float n2 = blk_reduce_sum(v * v, red);
    float inv = 1.f / sqrtf(n2);
    xh[g * DD + t] = bf16_rne(v * inv);
    if (t == 0) qInv[g] = inv;
}

// ---------- K1: proto, pn, self_sim ----------
__global__ __launch_bounds__(256) void proto_kernel(const float* __restrict__ x,
                                                    float* proto, float* pn, float* selfs) {
    __shared__ float red[256];
    int c = blockIdx.x, t = threadIdx.x;
    float s = 0.f;
    for (int j = 0; j < KS; j++) s += x[(long)(c * 133 + j) * DD + t];
    float p = s / 5.0f;
    proto[c * DD + t] = p;
    float n2 = blk_reduce_sum(p * p, red);
    float pv = p / sqrtf(n2);
    pn[c * DD + t] = pv;
    float ss = blk_reduce_sum(pv * pv, red);
    if (t == 0) selfs[c] = ss;
}

// ---------- K2: pre_sim argmax per query ----------
__global__ __launch_bounds__(256) void presim_kernel(const float* __restrict__ x,
                                                     const float* __restrict__ qInv,
                                                     const float* __restrict__ pn,
                                                     float* pre_max, int* pre_label) {
    __shared__ float qs[256];
    __shared__ float part[256];
    __shared__ float sims[64];
    int g = blockIdx.x, t = threadIdx.x;
    qs[t] = x[(long)qrow(g) * DD + t];
    __syncthreads();
    int c = t >> 2, tl = t & 3;
    float s = 0.f;
    for (int u = 0; u < 64; u++) s += qs[tl * 64 + u] * pn[c * DD + tl * 64 + u];
    part[t] = s; __syncthreads();
    if (tl == 0) sims[c] = part[t] + part[t + 1] + part[t + 2] + part[t + 3];
    __syncthreads();
    if (t == 0) {
        float best = sims[0]; int bi = 0;
        for (int c2 = 1; c2 < 64; c2++)
            if (sims[c2] > best) { best = sims[c2]; bi = c2; }
        pre_max[g] = best * qInv[g];
        pre_label[g] = bi;
    }
}

// ---------- K3: adapted prototypes — LDS-compacted member list ----------
__global__ __launch_bounds__(256) void adapt_proto_kernel(const float* __restrict__ x,
                                                          const float* __restrict__ proto,
                                                          const float* __restrict__ selfs,
                                                          const float* __restrict__ pre_max,
                                                          const int* __restrict__ pre_label,
                                                          float* apn) {
    __shared__ int lst[NQ];
    __shared__ float red[256];
    __shared__ int cnt_s;
    int c = blockIdx.x, t = threadIdx.x;
    if (t == 0) cnt_s = 0;
    __syncthreads();
    float lm = -INFINITY;
    for (int g = t; g < NQ; g += 256) {
        if (pre_label[g] == c) {
            int p = atomicAdd(&cnt_s, 1);
            lst[p] = g;
            lm = fmaxf(lm, pre_max[g]);
        }
    }
    float m = fmaxf(blk_reduce_max(lm, red), selfs[c]);   // barrier publishes lst/cnt_s
    int cnt = cnt_s;
    float ls = 0.f;
    for (int e = t; e < cnt; e += 256) ls += expf(pre_max[lst[e]] - m);
    float es = expf(selfs[c] - m);
    float Z = blk_reduce_sum(ls, red) + es;
    float acc = es * proto[c * DD + t];
    #pragma unroll 2
    for (int e = 0; e < cnt; e++) {
        int g = lst[e];
        acc += expf(pre_max[g] - m) * x[(long)qrow(g) * DD + t];
    }
    float ap = acc / Z;
    float n2 = blk_reduce_sum(ap * ap, red);
    apn[c * DD + t] = ap / sqrtf(n2);
}

// ---------- K4: bf16 MFMA coarse cosines, REGISTER-resident scan ----------
// Operand swap: mfma(cand_frag, query_frag) -> D[row=cand 4qd+r][col=query nn].
// Each lane owns query nn; its 4 acc values per tile are candidate scores ->
// scan happens straight out of the accumulator: ZERO LDS in the main loop.
// Scores packed to monotone u32 keys (22 value bits | 10-bit col): 12-reg list,
// 2-inst/step insert chain, tie-free merge (col bits make all keys distinct).
// LDS: 13.3 KB merge scratch only -> 6 blocks/CU (24 waves, was 16).
__global__ __launch_bounds__(256, 6) void simtopk_kernel(const unsigned short* __restrict__ xh,
                                                         int* __restrict__ topi4) {
    __shared__ unsigned int dump[4][13 * 64];   // per-wave 64 lanes x 12 keys, stride 13

    const int t = threadIdx.x;
    const int b = blockIdx.x;
    const int rb = b >> 3;          // 128 row-blocks of 64 rows
    const int ch = b & 7;           // column chunk
    const int row0 = rb * 64;
    const int col0 = ch * 1024;

    const int wv = t >> 6;
    const int lane = t & 63;
    const int qd = lane >> 4;
    const int nn = lane & 15;

    // Query fragments (MFMA **B** operand): lane holds Q[n=nn][k=kc*32+qd*8 ..+7]
    const int arow = (row0 + wv * 16 + nn) * DD;
    short8 qh[8];
    #pragma unroll
    for (int kc = 0; kc < 8; kc++)
        qh[kc] = *(const short8*)(xh + arow + kc * 32 + qd * 8);

    unsigned int keys[QK];
    #pragma unroll
    for (int s = 0; s < QK; s++) keys[s] = 0u;   // below any real score's key

    for (int tile = 0; tile < 64; ++tile) {
        const int cbase = col0 + tile * 16;
        const unsigned short* cp = xh + (cbase + nn) * DD;   // cand row nn of tile (A operand)
        f32x4 acc = {0.f, 0.f, 0.f, 0.f};
        #pragma unroll
        for (int kc = 0; kc < 8; kc++) {
            short8 cf = *(const short8*)(cp + kc * 32 + qd * 8);
            acc = __builtin_amdgcn_mfma_f32_16x16x32_bf16(cf, qh[kc], acc, 0, 0, 0);
        }
        // lane holds scores for query nn, candidates (tile*16 + 4qd + r)
        #pragma unroll
        for (int r = 0; r < 4; ++r) {
            unsigned int u = __float_as_uint(acc[r]);
            unsigned int key = u ^ (unsigned int)(((int)u >> 31) | 0x80000000);
            key = (key & 0xFFFFFC00u) | (unsigned int)(tile * 16 + 4 * qd + r);
            if (key > keys[QK - 1]) {
                unsigned int ck = key;
                #pragma unroll
                for (int p = 0; p < QK; ++p) {
                    bool sw = ck > keys[p];
                    unsigned int tmp = keys[p];
                    keys[p] = sw ? ck : keys[p];
                    ck = sw ? tmp : ck;
                }
            }
        }
    }

    // dump (wave-private, in-order DS: no barrier) + per-query 4-list merge.
    // Query nn's lists live at lanes nn, nn+16, nn+32, nn+48.
    unsigned int* dw = &dump[wv][0];
    #pragma unroll
    for (int s = 0; s < QK; s++) dw[lane * 13 + s] = keys[s];
    if (lane < 16) {
        const int g = row0 + wv * 16 + lane;
        const int b0 = (lane +  0) * 13;
        const int b1 = (lane + 16) * 13;
        const int b2 = (lane + 32) * 13;
        const int b3 = (lane + 48) * 13;
        int p0 = 0, p1 = 0, p2 = 0, p3 = 0;
        for (int s = 0; s < QK; s++) {
            unsigned int v0 = (p0 < QK) ? dw[b0 + p0] : 0u;
            unsigned int v1 = (p1 < QK) ? dw[b1 + p1] : 0u;
            unsigned int v2 = (p2 < QK) ? dw[b2 + p2] : 0u;
            unsigned int v3 = (p3 < QK) ? dw[b3 + p3] : 0u;
            unsigned int bv = v0; int bw = 0;
            if (v1 > bv) { bv = v1; bw = 1; }
            if (v2 > bv) { bv = v2; bw = 2; }
            if (v3 > bv) { bv = v3; bw = 3; }
            topi4[g * CAND + ch * QK + s] = col0 + (int)(bv & 1023u);
            if (bw == 0) p0++; else if (bw == 1) p1++; else if (bw == 2) p2++; else p3++;
        }
    }
}

// ---------- K5: exact fp32 rescoring, fully-coalesced (block = 1 query) ----------
// 64 lanes per candidate: one float4 wave-load = the whole 1 KB row, one line
// burst (was: 64 scattered lines per wave-load). 4 candidates in flight.
__global__ __launch_bounds__(256) void rescore_kernel(const float* __restrict__ x,
                                                      const float* __restrict__ qInv,
                                                      const int* __restrict__ topi4,
                                                      float* __restrict__ topv,
                                                      int* __restrict__ topi) {
    __shared__ float sc[CAND];
    __shared__ int   si[CAND];
    const int g = blockIdx.x;
    const int t = threadIdx.x;
    const int lane = t & 63;
    const int w = t >> 6;            // candidate sub-slot 0..3
    const float4 a4 = *(const float4*)(x + (long)qrow(g) * DD + lane * 4);
    const float qg = qInv[g];
    #pragma unroll 4
    for (int pass = 0; pass < CAND / 4; ++pass) {
        const int c = pass * 4 + w;
        int j = topi4[g * CAND + c];
        if ((unsigned)j >= NQ) j = 0;
        const float4 b4 = *(const float4*)(x + (long)qrow(j) * DD + lane * 4);
        float p = a4.x * b4.x + a4.y * b4.y + a4.z * b4.z + a4.w * b4.w;
        #pragma unroll
        for (int off = 32; off > 0; off >>= 1) p += __shfl_xor(p, off);
        if (lane == 0) { sc[c] = p * qInv[j] * qg; si[c] = j; }
    }
    __syncthreads();
    if (t == 0) {
        float Lv[KNB]; int Li[KNB];
        for (int s = 0; s < KNB; s++) { Lv[s] = -INFINITY; Li[s] = 0x7fffffff; }
        #pragma unroll 4
        for (int q = 0; q < CAND; q++) {
            float v = sc[q]; int idx = si[q];
            if (v > Lv[KNB - 1] || (v == Lv[KNB - 1] && idx < Li[KNB - 1])) {
                int p = KNB - 1;
                while (p > 0 && (Lv[p - 1] < v || (Lv[p - 1] == v && Li[p - 1] > idx))) {
                    Lv[p] = Lv[p - 1]; Li[p] = Li[p - 1]; p--;
                }
                Lv[p] = v; Li[p] = idx;
            }
        }
        for (int s = 0; s < KNB; s++) {
            topv[g * KNB + s] = Lv[s];
            topi[g * KNB + s] = Li[s];
        }
    }
}

// ---------- K6: mutual-kNN softmax, adapted query, final cos sims ----------
__global__ __launch_bounds__(256) void final_kernel(const float* __restrict__ x,
                                                    const float* __restrict__ apn,
                                                    const float* __restrict__ topv,
                                                    const int* __restrict__ topi,
                                                    const float* __restrict__ tao_raw,
                                                    float* out) {
    __shared__ float tv[KNB]; __shared__ int ti[KNB]; __shared__ float w[KNB];
    __shared__ float aq[256]; __shared__ float red[256];
    int i = blockIdx.x, t = threadIdx.x;
    if (t < KNB) {
        tv[t] = topv[i * KNB + t];
        int j = topi[i * KNB + t];
        ti[t] = ((unsigned)j < NQ) ? j : 0;
    }
    __syncthreads();
    if (t < KNB) {
        int j = ti[t];
        bool mut = false;
        for (int s = 0; s < KNB; s++) mut = mut || (topi[j * KNB + s] == i);
        w[t] = mut ? tv[t] : -INFINITY;
    }
    __syncthreads();
    if (t == 0) {
        float m = -INFINITY;
        for (int s = 0; s < KNB; s++) m = fmaxf(m, w[s]);
        float e[KNB]; float Z = 0.f;
        for (int s = 0; s < KNB; s++) { e[s] = expf(w[s] - m); Z += e[s]; }
        for (int s = 0; s < KNB; s++) w[s] = e[s] / Z;
    }
    __syncthreads();
    float a = 0.f;
    for (int s = 0; s < KNB; s++) {
        float ws = w[s];
        if (ws != 0.f) a += ws * x[(long)qrow(ti[s]) * DD + t];
    }
    aq[t] = a;
    float n2 = blk_reduce_sum(a * a, red);
    float inv = 1.f / sqrtf(n2);
    int c = t >> 2, tl = t & 3;
    float sdot = 0.f;
    for (int u = 0; u < 64; u++) sdot += aq[tl * 64 + u] * apn[c * DD + tl * 64 + u];
    red[t] = sdot; __syncthreads();
    if (tl == 0) {
        float sv = red[t] + red[t + 1] + red[t + 2] + red[t + 3];
        out[i * NCLS + c] = tao_raw[0] * sv * inv;
    }
}

extern "C" void kernel_launch(void* const* d_in, const int* in_sizes, int n_in,
                              void* d_out, int out_size, void* d_ws, size_t ws_size,
                              hipStream_t stream) {
    (void)in_sizes; (void)n_in; (void)out_size;
    const float* x   = (const float*)d_in[0];
    const float* tao = (const float*)d_in[1];
    float* out = (float*)d_out;

    char* ws = (char*)d_ws;
    size_t off = 0;
    auto carve = [&](size_t bytes) {
        void* p = ws + off;
        off = (off + bytes + 255) & ~(size_t)255;
        return p;
    };
    float*          proto   = (float*)carve(NCLS * DD * 4);
    float*          pn      = (float*)carve(NCLS * DD * 4);
    float*          selfs   = (float*)carve(NCLS * 4);
    float*          qInv    = (float*)carve(NQ * 4);
    float*          pre_max = (float*)carve(NQ * 4);
    int*            pre_lab = (int*)carve(NQ * 4);
    float*          apn     = (float*)carve(NCLS * DD * 4);
    unsigned short* xh      = (unsigned short*)carve((size_t)NQ * DD * 2);
    int*            topi4   = (int*)carve((size_t)NQ * CAND * 4);
    float*          topv    = (float*)carve((size_t)NQ * KNB * 4);
    int*            topi    = (int*)carve((size_t)NQ * KNB * 4);
    if (off > ws_size) return;

    split_kernel<<<NQ, 256, 0, stream>>>(x, xh, qInv);
    proto_kernel<<<NCLS, 256, 0, stream>>>(x, proto, pn, selfs);
    presim_kernel<<<NQ, 256, 0, stream>>>(x, qInv, pn, pre_max, pre_lab);
    adapt_proto_kernel<<<NCLS, 256, 0, stream>>>(x, proto, selfs, pre_max, pre_lab, apn);
    simtopk_kernel<<<NQ / 64 * NCH, 256, 0, stream>>>(xh, topi4);
    rescore_kernel<<<NQ, 256, 0, stream>>>(x, qInv, topi4, topv, topi);
    final_kernel<<<NQ, 256, 0, stream>>>(x, apn, topv, topi, tao, out);
}